// Round 1
// baseline (292.065 us; speedup 1.0000x reference)
//
#include <hip/hip_runtime.h>

#define Bn 4096
#define En 1024
#define On 16
#define Hn 1024

#define BM 128
#define BN 128
#define BK 32

using floatx4 = __attribute__((ext_vector_type(4))) float;
using float4v = __attribute__((ext_vector_type(4))) float;
using bf16x8  = __attribute__((ext_vector_type(8))) __bf16;
using short4v = __attribute__((ext_vector_type(4))) short;
using short8v = __attribute__((ext_vector_type(8))) short;

__device__ inline unsigned short f2bf(float f) {
    unsigned u = __builtin_bit_cast(unsigned, f);
    u += 0x7fffu + ((u >> 16) & 1u);   // RNE to bf16 (inputs finite)
    return (unsigned short)(u >> 16);
}

// ---------------- bucket examples by op ----------------
__global__ void bucket_kernel(const int* __restrict__ op_idx,
                              int* __restrict__ sorted_idx,
                              int* __restrict__ offsets) {
    __shared__ int cnt[On], cur[On], off[On + 1];
    int tid = threadIdx.x;
    if (tid < On) { cnt[tid] = 0; cur[tid] = 0; }
    __syncthreads();
    for (int i = tid; i < Bn; i += blockDim.x) atomicAdd(&cnt[op_idx[i]], 1);
    __syncthreads();
    if (tid == 0) {
        int s = 0;
        for (int o = 0; o < On; ++o) { off[o] = s; s += cnt[o]; }
        off[On] = s;
    }
    __syncthreads();
    for (int i = tid; i < Bn; i += blockDim.x) {
        int o = op_idx[i];
        int p = off[o] + atomicAdd(&cur[o], 1);
        sorted_idx[p] = i;
    }
    if (tid <= On) offsets[tid] = off[tid];
}

// ---------------- layer 1: h1 = relu(x[sel] @ W1[:,o,:] + b1[o]) ----------------
// LDS layout granule-major: As[k/8][row][k%8] -> frag reads are 256B contiguous per 16-lane phase.
__global__ __launch_bounds__(256) void gemm1_kernel(
    const float* __restrict__ x, const float* __restrict__ W1,
    const float* __restrict__ bias1, const int* __restrict__ sorted_idx,
    const int* __restrict__ offsets, unsigned short* __restrict__ h1) {
    int o = blockIdx.z;
    int off = offsets[o];
    int cnt = offsets[o + 1] - off;
    int m0 = blockIdx.y * BM;
    if (m0 >= cnt) return;
    int n0 = blockIdx.x * BN;

    __shared__ unsigned short As[4][BM][8];
    __shared__ unsigned short Bs[4][BN][8];

    int tid = threadIdx.x;
    // A staging: row ar, 16 floats starting at col ag*8
    int ar = tid >> 1;
    int ag = (tid & 1) * 2;
    const float* arow = nullptr;
    if (m0 + ar < cnt) arow = x + (size_t)sorted_idx[off + m0 + ar] * En + ag * 8;
    // B staging: 4 k-rows starting at bk, 4 n-cols starting at bn (transpose into LDS)
    int bk = (tid & 7) * 4;
    int bn = (tid >> 3) * 4;
    const float* bbase = W1 + ((size_t)bk * On + o) * Hn + n0 + bn;

    floatx4 acc[4][4] = {};

    int lane = tid & 63;
    int wave = tid >> 6;
    int wm = (wave >> 1) * 64;
    int wn = (wave & 1) * 64;
    int l15 = lane & 15;
    int kg = lane >> 4;

    for (int kt = 0; kt < En; kt += BK) {
        // stage A
        short8v a0 = {}, a1 = {};
        if (arow) {
            const float4v* p = (const float4v*)(arow + kt);
            float4v f0 = p[0], f1 = p[1], f2 = p[2], f3 = p[3];
#pragma unroll
            for (int i = 0; i < 4; ++i) {
                a0[i] = (short)f2bf(f0[i]); a0[4 + i] = (short)f2bf(f1[i]);
                a1[i] = (short)f2bf(f2[i]); a1[4 + i] = (short)f2bf(f3[i]);
            }
        }
        *(short8v*)&As[ag][ar][0] = a0;
        *(short8v*)&As[ag + 1][ar][0] = a1;
        // stage B (transpose 4x4 micro-tile)
        {
            const float* bp = bbase + (size_t)kt * (On * Hn);
            float4v r0 = *(const float4v*)(bp);
            float4v r1 = *(const float4v*)(bp + (size_t)(On * Hn));
            float4v r2 = *(const float4v*)(bp + (size_t)(2 * On * Hn));
            float4v r3 = *(const float4v*)(bp + (size_t)(3 * On * Hn));
#pragma unroll
            for (int j = 0; j < 4; ++j) {
                short4v v = { (short)f2bf(r0[j]), (short)f2bf(r1[j]),
                              (short)f2bf(r2[j]), (short)f2bf(r3[j]) };
                *(short4v*)&Bs[bk >> 3][bn + j][bk & 4] = v;
            }
        }
        __syncthreads();
        bf16x8 af[4], bfr[4];
#pragma unroll
        for (int mt = 0; mt < 4; ++mt) af[mt] = *(const bf16x8*)&As[kg][wm + mt * 16 + l15][0];
#pragma unroll
        for (int nt = 0; nt < 4; ++nt) bfr[nt] = *(const bf16x8*)&Bs[kg][wn + nt * 16 + l15][0];
#pragma unroll
        for (int mt = 0; mt < 4; ++mt)
#pragma unroll
            for (int nt = 0; nt < 4; ++nt)
                acc[mt][nt] = __builtin_amdgcn_mfma_f32_16x16x32_bf16(af[mt], bfr[nt], acc[mt][nt], 0, 0, 0);
        __syncthreads();
    }

    // epilogue: bias + relu -> h1 (bf16, sorted order)
    int r4 = (lane >> 4) * 4;
#pragma unroll
    for (int nt = 0; nt < 4; ++nt) {
        int col = n0 + wn + nt * 16 + l15;
        float bv = bias1[o * Hn + col];
#pragma unroll
        for (int mt = 0; mt < 4; ++mt) {
#pragma unroll
            for (int r = 0; r < 4; ++r) {
                int row = m0 + wm + mt * 16 + r4 + r;
                if (row < cnt) {
                    float v = acc[mt][nt][r] + bv;
                    v = v > 0.f ? v : 0.f;
                    h1[(size_t)(off + row) * Hn + col] = f2bf(v);
                }
            }
        }
    }
}

// ---------------- layer 2: out[sel] = relu(h1 @ W2[:,o,:] + b2[o]) ----------------
__global__ __launch_bounds__(256) void gemm2_kernel(
    const unsigned short* __restrict__ h1, const float* __restrict__ W2,
    const float* __restrict__ bias2, const int* __restrict__ sorted_idx,
    const int* __restrict__ offsets, float* __restrict__ out) {
    int o = blockIdx.z;
    int off = offsets[o];
    int cnt = offsets[o + 1] - off;
    int m0 = blockIdx.y * BM;
    if (m0 >= cnt) return;
    int n0 = blockIdx.x * BN;

    __shared__ unsigned short As[4][BM][8];
    __shared__ unsigned short Bs[4][BN][8];

    int tid = threadIdx.x;
    int ar = tid >> 1;
    int ag = (tid & 1) * 2;
    const unsigned short* arow = nullptr;
    if (m0 + ar < cnt) arow = h1 + (size_t)(off + m0 + ar) * Hn + ag * 8;
    int bk = (tid & 7) * 4;
    int bn = (tid >> 3) * 4;
    const float* bbase = W2 + ((size_t)bk * On + o) * Hn + n0 + bn;

    floatx4 acc[4][4] = {};

    int lane = tid & 63;
    int wave = tid >> 6;
    int wm = (wave >> 1) * 64;
    int wn = (wave & 1) * 64;
    int l15 = lane & 15;
    int kg = lane >> 4;

    for (int kt = 0; kt < Hn; kt += BK) {
        short8v a0 = {}, a1 = {};
        if (arow) {
            a0 = *(const short8v*)(arow + kt);
            a1 = *(const short8v*)(arow + kt + 8);
        }
        *(short8v*)&As[ag][ar][0] = a0;
        *(short8v*)&As[ag + 1][ar][0] = a1;
        {
            const float* bp = bbase + (size_t)kt * (On * Hn);
            float4v r0 = *(const float4v*)(bp);
            float4v r1 = *(const float4v*)(bp + (size_t)(On * Hn));
            float4v r2 = *(const float4v*)(bp + (size_t)(2 * On * Hn));
            float4v r3 = *(const float4v*)(bp + (size_t)(3 * On * Hn));
#pragma unroll
            for (int j = 0; j < 4; ++j) {
                short4v v = { (short)f2bf(r0[j]), (short)f2bf(r1[j]),
                              (short)f2bf(r2[j]), (short)f2bf(r3[j]) };
                *(short4v*)&Bs[bk >> 3][bn + j][bk & 4] = v;
            }
        }
        __syncthreads();
        bf16x8 af[4], bfr[4];
#pragma unroll
        for (int mt = 0; mt < 4; ++mt) af[mt] = *(const bf16x8*)&As[kg][wm + mt * 16 + l15][0];
#pragma unroll
        for (int nt = 0; nt < 4; ++nt) bfr[nt] = *(const bf16x8*)&Bs[kg][wn + nt * 16 + l15][0];
#pragma unroll
        for (int mt = 0; mt < 4; ++mt)
#pragma unroll
            for (int nt = 0; nt < 4; ++nt)
                acc[mt][nt] = __builtin_amdgcn_mfma_f32_16x16x32_bf16(af[mt], bfr[nt], acc[mt][nt], 0, 0, 0);
        __syncthreads();
    }

    int r4 = (lane >> 4) * 4;
    float bv[4];
#pragma unroll
    for (int nt = 0; nt < 4; ++nt) bv[nt] = bias2[o * Hn + n0 + wn + nt * 16 + l15];
#pragma unroll
    for (int mt = 0; mt < 4; ++mt) {
#pragma unroll
        for (int r = 0; r < 4; ++r) {
            int row = m0 + wm + mt * 16 + r4 + r;
            if (row < cnt) {
                int b = sorted_idx[off + row];
                float* orow = out + (size_t)b * Hn + n0 + wn + l15;
#pragma unroll
                for (int nt = 0; nt < 4; ++nt) {
                    float v = acc[mt][nt][r] + bv[nt];
                    orow[nt * 16] = v > 0.f ? v : 0.f;
                }
            }
        }
    }
}

extern "C" void kernel_launch(void* const* d_in, const int* in_sizes, int n_in,
                              void* d_out, int out_size, void* d_ws, size_t ws_size,
                              hipStream_t stream) {
    const float* x      = (const float*)d_in[0];
    const int*   op_idx = (const int*)d_in[1];
    const float* W1     = (const float*)d_in[2];
    const float* bias1  = (const float*)d_in[3];
    const float* W2     = (const float*)d_in[4];
    const float* bias2  = (const float*)d_in[5];
    float* out = (float*)d_out;

    char* ws = (char*)d_ws;
    int* offsets    = (int*)ws;                 // 17 ints
    int* sorted_idx = (int*)(ws + 256);         // 4096 ints
    unsigned short* h1 = (unsigned short*)(ws + 256 + 16384);  // [Bn][Hn] bf16 = 8 MB

    hipLaunchKernelGGL(bucket_kernel, dim3(1), dim3(1024), 0, stream,
                       op_idx, sorted_idx, offsets);
    dim3 grid(Hn / BN, (Bn + BM - 1) / BM, On);
    hipLaunchKernelGGL(gemm1_kernel, grid, dim3(256), 0, stream,
                       x, W1, bias1, sorted_idx, offsets, h1);
    hipLaunchKernelGGL(gemm2_kernel, grid, dim3(256), 0, stream,
                       h1, W2, bias2, sorted_idx, offsets, out);
}

// Round 2
// 262.967 us; speedup vs baseline: 1.1107x; 1.1107x over previous
//
#include <hip/hip_runtime.h>

#define Bn 4096
#define En 1024
#define On 16
#define Hn 1024
#define OHn (On * Hn)

#define BM 64
#define BN 128
#define BK 64

using floatx4 = __attribute__((ext_vector_type(4))) float;
using float4v = __attribute__((ext_vector_type(4))) float;
using bf16x8  = __attribute__((ext_vector_type(8))) __bf16;
using short8v = __attribute__((ext_vector_type(8))) short;

__device__ inline unsigned short f2bf(float f) {
    unsigned u = __builtin_bit_cast(unsigned, f);
    u += 0x7fffu + ((u >> 16) & 1u);   // RNE to bf16 (inputs finite)
    return (unsigned short)(u >> 16);
}

// ---------------- bucket examples by op ----------------
__global__ void bucket_kernel(const int* __restrict__ op_idx,
                              int* __restrict__ sorted_idx,
                              int* __restrict__ offsets) {
    __shared__ int cnt[On], cur[On], off[On + 1];
    int tid = threadIdx.x;
    if (tid < On) { cnt[tid] = 0; cur[tid] = 0; }
    __syncthreads();
    for (int i = tid; i < Bn; i += blockDim.x) atomicAdd(&cnt[op_idx[i]], 1);
    __syncthreads();
    if (tid == 0) {
        int s = 0;
        for (int o = 0; o < On; ++o) { off[o] = s; s += cnt[o]; }
        off[On] = s;
    }
    __syncthreads();
    for (int i = tid; i < Bn; i += blockDim.x) {
        int o = op_idx[i];
        int p = off[o] + atomicAdd(&cur[o], 1);
        sorted_idx[p] = i;
    }
    if (tid <= On) offsets[tid] = off[tid];
}

// ---------------- layer 1: h1 = relu(x[sel] @ W1[:,o,:] + b1[o]) ----------------
// LDS granule-major: As[g][row][k%8]; all ds accesses are b128 with
// consecutive-lane => consecutive-16B (conflict-free).
__global__ __launch_bounds__(256) void gemm1_kernel(
    const float* __restrict__ x, const float* __restrict__ W1,
    const float* __restrict__ bias1, const int* __restrict__ sorted_idx,
    const int* __restrict__ offsets, unsigned short* __restrict__ h1) {
    int o = blockIdx.z;
    int off = offsets[o];
    int cnt = offsets[o + 1] - off;
    int m0 = blockIdx.y * BM;
    if (m0 >= cnt) return;
    int n0 = blockIdx.x * BN;

    __shared__ unsigned short As[8][BM][8];
    __shared__ unsigned short Bs[8][BN][8];

    int tid = threadIdx.x;

    // A staging: thread owns cells (g=ag, row=arow) and (g=ag+4, row=arow)
    int arow = tid & 63;
    int ag = tid >> 6;   // 0..3
    const float* aptr = nullptr;
    if (m0 + arow < cnt) aptr = x + (size_t)sorted_idx[off + m0 + arow] * En;

    // B staging: thread owns n=bn, granules bg0..bg0+3 (per-thread k in regs)
    int bn = tid & 127;
    int bg0 = (tid >> 7) * 4;   // 0 or 4
    const float* bptr = W1 + (size_t)o * Hn + n0 + bn;

    float a_pre[16] = {};
    float b_pre[32];

    floatx4 acc[2][4] = {};
    int lane = tid & 63;
    int wave = tid >> 6;
    int wm = (wave >> 1) * 32;
    int wn = (wave & 1) * 64;
    int l15 = lane & 15;
    int kg = lane >> 4;

    // prologue: load tile 0 into regs
#pragma unroll
    for (int i = 0; i < 2; ++i) {
        int k = (ag + 4 * i) * 8;
        if (aptr) {
            *(float4v*)&a_pre[i * 8]     = *(const float4v*)(aptr + k);
            *(float4v*)&a_pre[i * 8 + 4] = *(const float4v*)(aptr + k + 4);
        }
    }
#pragma unroll
    for (int g = 0; g < 4; ++g)
#pragma unroll
        for (int j = 0; j < 8; ++j)
            b_pre[g * 8 + j] = bptr[(size_t)((bg0 + g) * 8 + j) * OHn];

    for (int kt = 0; kt < En; kt += BK) {
        // cvt + store current tile to LDS (b128, conflict-free)
#pragma unroll
        for (int i = 0; i < 2; ++i) {
            short8v v;
#pragma unroll
            for (int j = 0; j < 8; ++j) v[j] = (short)f2bf(a_pre[i * 8 + j]);
            *(short8v*)&As[ag + 4 * i][arow][0] = v;
        }
#pragma unroll
        for (int g = 0; g < 4; ++g) {
            short8v v;
#pragma unroll
            for (int j = 0; j < 8; ++j) v[j] = (short)f2bf(b_pre[g * 8 + j]);
            *(short8v*)&Bs[bg0 + g][bn][0] = v;
        }
        __syncthreads();

        // prefetch next tile into regs (overlaps MFMA below)
        int ktn = kt + BK;
        if (ktn < En) {
#pragma unroll
            for (int i = 0; i < 2; ++i) {
                int k = ktn + (ag + 4 * i) * 8;
                if (aptr) {
                    *(float4v*)&a_pre[i * 8]     = *(const float4v*)(aptr + k);
                    *(float4v*)&a_pre[i * 8 + 4] = *(const float4v*)(aptr + k + 4);
                }
            }
#pragma unroll
            for (int g = 0; g < 4; ++g)
#pragma unroll
                for (int j = 0; j < 8; ++j)
                    b_pre[g * 8 + j] = bptr[(size_t)(ktn + (bg0 + g) * 8 + j) * OHn];
        }

        // compute from LDS: 2 k-steps of K=32
#pragma unroll
        for (int ks = 0; ks < 2; ++ks) {
            int g = ks * 4 + kg;
            bf16x8 af[2], bfr[4];
#pragma unroll
            for (int mt = 0; mt < 2; ++mt) af[mt] = *(const bf16x8*)&As[g][wm + mt * 16 + l15][0];
#pragma unroll
            for (int nt = 0; nt < 4; ++nt) bfr[nt] = *(const bf16x8*)&Bs[g][wn + nt * 16 + l15][0];
#pragma unroll
            for (int mt = 0; mt < 2; ++mt)
#pragma unroll
                for (int nt = 0; nt < 4; ++nt)
                    acc[mt][nt] = __builtin_amdgcn_mfma_f32_16x16x32_bf16(af[mt], bfr[nt], acc[mt][nt], 0, 0, 0);
        }
        __syncthreads();
    }

    // epilogue: bias + relu -> h1 (bf16, sorted order)
    int r4 = (lane >> 4) * 4;
#pragma unroll
    for (int nt = 0; nt < 4; ++nt) {
        int col = n0 + wn + nt * 16 + l15;
        float bv = bias1[o * Hn + col];
#pragma unroll
        for (int mt = 0; mt < 2; ++mt) {
#pragma unroll
            for (int r = 0; r < 4; ++r) {
                int row = m0 + wm + mt * 16 + r4 + r;
                if (row < cnt) {
                    float v = acc[mt][nt][r] + bv;
                    v = v > 0.f ? v : 0.f;
                    h1[(size_t)(off + row) * Hn + col] = f2bf(v);
                }
            }
        }
    }
}

// ---------------- layer 2: out[sel] = relu(h1 @ W2[:,o,:] + b2[o]) ----------------
__global__ __launch_bounds__(256) void gemm2_kernel(
    const unsigned short* __restrict__ h1, const float* __restrict__ W2,
    const float* __restrict__ bias2, const int* __restrict__ sorted_idx,
    const int* __restrict__ offsets, float* __restrict__ out) {
    int o = blockIdx.z;
    int off = offsets[o];
    int cnt = offsets[o + 1] - off;
    int m0 = blockIdx.y * BM;
    if (m0 >= cnt) return;
    int n0 = blockIdx.x * BN;

    __shared__ unsigned short As[8][BM][8];
    __shared__ unsigned short Bs[8][BN][8];

    int tid = threadIdx.x;

    int arow = tid & 63;
    int ag = tid >> 6;
    const unsigned short* aptr = nullptr;
    if (m0 + arow < cnt) aptr = h1 + (size_t)(off + m0 + arow) * Hn;

    int bn = tid & 127;
    int bg0 = (tid >> 7) * 4;
    const float* bptr = W2 + (size_t)o * Hn + n0 + bn;

    short8v a_pre[2] = {};
    float b_pre[32];

    floatx4 acc[2][4] = {};
    int lane = tid & 63;
    int wave = tid >> 6;
    int wm = (wave >> 1) * 32;
    int wn = (wave & 1) * 64;
    int l15 = lane & 15;
    int kg = lane >> 4;

    // prologue
#pragma unroll
    for (int i = 0; i < 2; ++i)
        if (aptr) a_pre[i] = *(const short8v*)(aptr + (ag + 4 * i) * 8);
#pragma unroll
    for (int g = 0; g < 4; ++g)
#pragma unroll
        for (int j = 0; j < 8; ++j)
            b_pre[g * 8 + j] = bptr[(size_t)((bg0 + g) * 8 + j) * OHn];

    for (int kt = 0; kt < Hn; kt += BK) {
#pragma unroll
        for (int i = 0; i < 2; ++i)
            *(short8v*)&As[ag + 4 * i][arow][0] = a_pre[i];
#pragma unroll
        for (int g = 0; g < 4; ++g) {
            short8v v;
#pragma unroll
            for (int j = 0; j < 8; ++j) v[j] = (short)f2bf(b_pre[g * 8 + j]);
            *(short8v*)&Bs[bg0 + g][bn][0] = v;
        }
        __syncthreads();

        int ktn = kt + BK;
        if (ktn < Hn) {
#pragma unroll
            for (int i = 0; i < 2; ++i)
                if (aptr) a_pre[i] = *(const short8v*)(aptr + ktn + (ag + 4 * i) * 8);
#pragma unroll
            for (int g = 0; g < 4; ++g)
#pragma unroll
                for (int j = 0; j < 8; ++j)
                    b_pre[g * 8 + j] = bptr[(size_t)(ktn + (bg0 + g) * 8 + j) * OHn];
        }

#pragma unroll
        for (int ks = 0; ks < 2; ++ks) {
            int g = ks * 4 + kg;
            bf16x8 af[2], bfr[4];
#pragma unroll
            for (int mt = 0; mt < 2; ++mt) af[mt] = *(const bf16x8*)&As[g][wm + mt * 16 + l15][0];
#pragma unroll
            for (int nt = 0; nt < 4; ++nt) bfr[nt] = *(const bf16x8*)&Bs[g][wn + nt * 16 + l15][0];
#pragma unroll
            for (int mt = 0; mt < 2; ++mt)
#pragma unroll
                for (int nt = 0; nt < 4; ++nt)
                    acc[mt][nt] = __builtin_amdgcn_mfma_f32_16x16x32_bf16(af[mt], bfr[nt], acc[mt][nt], 0, 0, 0);
        }
        __syncthreads();
    }

    // epilogue: bias + relu, scatter rows back to original order (fp32)
    int r4 = (lane >> 4) * 4;
    float bv[4];
#pragma unroll
    for (int nt = 0; nt < 4; ++nt) bv[nt] = bias2[o * Hn + n0 + wn + nt * 16 + l15];
#pragma unroll
    for (int mt = 0; mt < 2; ++mt) {
#pragma unroll
        for (int r = 0; r < 4; ++r) {
            int row = m0 + wm + mt * 16 + r4 + r;
            if (row < cnt) {
                int b = sorted_idx[off + row];
                float* orow = out + (size_t)b * Hn + n0 + wn + l15;
#pragma unroll
                for (int nt = 0; nt < 4; ++nt) {
                    float v = acc[mt][nt][r] + bv[nt];
                    orow[nt * 16] = v > 0.f ? v : 0.f;
                }
            }
        }
    }
}

extern "C" void kernel_launch(void* const* d_in, const int* in_sizes, int n_in,
                              void* d_out, int out_size, void* d_ws, size_t ws_size,
                              hipStream_t stream) {
    const float* x      = (const float*)d_in[0];
    const int*   op_idx = (const int*)d_in[1];
    const float* W1     = (const float*)d_in[2];
    const float* bias1  = (const float*)d_in[3];
    const float* W2     = (const float*)d_in[4];
    const float* bias2  = (const float*)d_in[5];
    float* out = (float*)d_out;

    char* ws = (char*)d_ws;
    int* offsets    = (int*)ws;                 // 17 ints
    int* sorted_idx = (int*)(ws + 256);         // 4096 ints
    unsigned short* h1 = (unsigned short*)(ws + 256 + 16384);  // [Bn][Hn] bf16 = 8 MB

    hipLaunchKernelGGL(bucket_kernel, dim3(1), dim3(1024), 0, stream,
                       op_idx, sorted_idx, offsets);
    dim3 grid(Hn / BN, Bn / BM, On);
    hipLaunchKernelGGL(gemm1_kernel, grid, dim3(256), 0, stream,
                       x, W1, bias1, sorted_idx, offsets, h1);
    hipLaunchKernelGGL(gemm2_kernel, grid, dim3(256), 0, stream,
                       h1, W2, bias2, sorted_idx, offsets, out);
}